// Round 6
// baseline (305.811 us; speedup 1.0000x reference)
//
#include <hip/hip_runtime.h>
#include <stdint.h>

#define N_Q 16384
#define M_P 1024
#define D_K 1024

typedef __attribute__((ext_vector_type(8))) __bf16 bf16x8;
typedef __attribute__((ext_vector_type(4))) float floatx4;
typedef __attribute__((ext_vector_type(8))) unsigned short ushort8v;

#define AS1 __attribute__((address_space(1)))
#define AS3 __attribute__((address_space(3)))

__device__ __forceinline__ unsigned short f2bf(float f) {
    unsigned int u = __float_as_uint(f);
    u += 0x7fffu + ((u >> 16) & 1u);   // round-to-nearest-even
    return (unsigned short)(u >> 16);
}
__device__ __forceinline__ float bf2f(unsigned short h) {
    return __uint_as_float(((unsigned int)h) << 16);
}

// ---------------------------------------------------------------------------
// Fused convert. Blocks [0,2048): query fp32 -> bf16 hi/lo, 4 float8s/thread.
// Blocks [2048,3072): proto rows + p2[m].
// ---------------------------------------------------------------------------
__global__ __launch_bounds__(256) void convert_all_kernel(
    const float* __restrict__ query, unsigned short* __restrict__ qh,
    unsigned short* __restrict__ ql, const float* __restrict__ proto,
    unsigned short* __restrict__ ph, unsigned short* __restrict__ pl,
    float* __restrict__ p2) {
    __shared__ float sred[4];
    int b = blockIdx.x;
    int t = threadIdx.x;
    if (b < 2048) {
        size_t base = (size_t)b * 1024 + t;   // float8 index
#pragma unroll
        for (int k = 0; k < 4; ++k) {
            size_t idx = base + (size_t)k * 256;
            const floatx4* src = (const floatx4*)query + idx * 2;
            floatx4 v0 = __builtin_nontemporal_load(src);
            floatx4 v1 = __builtin_nontemporal_load(src + 1);
            ushort8v h, l;
            h[0] = f2bf(v0.x); l[0] = f2bf(v0.x - bf2f(h[0]));
            h[1] = f2bf(v0.y); l[1] = f2bf(v0.y - bf2f(h[1]));
            h[2] = f2bf(v0.z); l[2] = f2bf(v0.z - bf2f(h[2]));
            h[3] = f2bf(v0.w); l[3] = f2bf(v0.w - bf2f(h[3]));
            h[4] = f2bf(v1.x); l[4] = f2bf(v1.x - bf2f(h[4]));
            h[5] = f2bf(v1.y); l[5] = f2bf(v1.y - bf2f(h[5]));
            h[6] = f2bf(v1.z); l[6] = f2bf(v1.z - bf2f(h[6]));
            h[7] = f2bf(v1.w); l[7] = f2bf(v1.w - bf2f(h[7]));
            ((ushort8v*)qh)[idx] = h;   // re-read by GEMM: keep cacheable
            ((ushort8v*)ql)[idx] = l;
        }
    } else {
        int m = b - 2048;
        size_t base4 = (size_t)m * (D_K / 4) + t;
        float4 v = ((const float4*)proto)[base4];
        ushort4 h, l;
        h.x = f2bf(v.x); l.x = f2bf(v.x - bf2f(h.x));
        h.y = f2bf(v.y); l.y = f2bf(v.y - bf2f(h.y));
        h.z = f2bf(v.z); l.z = f2bf(v.z - bf2f(h.z));
        h.w = f2bf(v.w); l.w = f2bf(v.w - bf2f(h.w));
        ((ushort4*)ph)[base4] = h;
        ((ushort4*)pl)[base4] = l;
        float sq = v.x * v.x + v.y * v.y + v.z * v.z + v.w * v.w;
#pragma unroll
        for (int off = 1; off < 64; off <<= 1) sq += __shfl_xor(sq, off);
        if ((t & 63) == 0) sred[t >> 6] = sq;
        __syncthreads();
        if (t == 0) p2[m] = sred[0] + sred[1] + sred[2] + sred[3];
    }
}

// ---------------------------------------------------------------------------
// FUSED GEMM + SOFTMAX.
// 512 blocks x 512 threads (8 waves). Block b owns rows [32b, 32b+32) and
// ALL 1024 cols: the whole softmax row stays in registers -> logits never
// round-trip through HBM (saves 128 MiB + one dispatch vs R5).
// Columns in 2 passes of 512; wave w owns cols [pass*512 + w*64, +64).
// acc[pass][i][j] : 2*2*4 floatx4 = 64 acc regs/thread (AGPR side).
// Per K-chunk (BK=32) per wave: A 4 + B 8 ds_read_b128, 24 MFMA (3-term).
// Staging keeps R4's verified pattern: quad-coalesced global (lane quad =
// one row's 64B) + XOR swizzle (measured 0 bank conflicts).
// LDS: A 4KB + B 64KB + 2KB reductions = 70KB -> 2 blocks/CU at
// __launch_bounds__(512,4) (VGPR cap 128).
// Epilogue: logits = 2*qp - p2; per-row max/sum via rsel-shuffles (lanes
// l^{1,2,4,8} share the same C-row) + 8-wave LDS combine; __expf; one
// nontemporal 64 MiB write of final probabilities.
// ---------------------------------------------------------------------------
__global__ __launch_bounds__(512, 4) void fused_gemm_softmax_kernel(
    const unsigned short* __restrict__ qh, const unsigned short* __restrict__ ql,
    const unsigned short* __restrict__ ph, const unsigned short* __restrict__ pl,
    const float* __restrict__ p2, float* __restrict__ out) {
    __shared__ unsigned short sA[2 * 1024];    // A hi | A lo   (32 rows x 32 K)
    __shared__ unsigned short sB[2 * 16384];   // B hi | B lo   (512 rows x 32 K)
    __shared__ float wred[8 * 32];             // per-wave row max partials
    __shared__ float wsum[8 * 32];             // per-wave row sum partials

    const int tid = threadIdx.x;
    const int wave = tid >> 6;
    const int lane = tid & 63;
    const int row0 = blockIdx.x * 32;

    // Staging lane offsets: quad-coalesced + XOR swizzle (R4-verified).
    const int rl = lane >> 2;
    const int cio = (lane & 3) ^ ((lane >> 3) & 3);
    const size_t laneoff = (size_t)rl * D_K + cio * 8;

    // Compute-side swizzled granule.
    const int rsel = lane & 15;
    const int kq = lane >> 4;
    const int gsw = 4 * rsel + (kq ^ ((rsel >> 1) & 3));
    const int fragoff = gsw * 8;  // shorts

    floatx4 zero = {0.0f, 0.0f, 0.0f, 0.0f};
    floatx4 acc[2][2][4];
#pragma unroll
    for (int p = 0; p < 2; ++p)
#pragma unroll
        for (int i = 0; i < 2; ++i)
#pragma unroll
            for (int j = 0; j < 4; ++j) acc[p][i][j] = zero;

#pragma unroll
    for (int pass = 0; pass < 2; ++pass) {
#pragma unroll 1
        for (int kt = 0; kt < D_K / 32; ++kt) {
            const int kbase = kt * 32;
            // ---- stage B: wave w handles subtiles w*4+u (hi & lo) ----
#pragma unroll
            for (int u = 0; u < 4; ++u) {
                const int s = wave * 4 + u;
                const size_t goff = (size_t)(pass * 512 + s * 16) * D_K + kbase + laneoff;
                __builtin_amdgcn_global_load_lds(
                    (const AS1 unsigned int*)(const void*)(ph + goff),
                    (AS3 unsigned int*)(void*)(sB + s * 512), 16, 0, 0);
                __builtin_amdgcn_global_load_lds(
                    (const AS1 unsigned int*)(const void*)(pl + goff),
                    (AS3 unsigned int*)(void*)(sB + 16384 + s * 512), 16, 0, 0);
            }
            // ---- stage A: waves 0,1 -> hi subtile w; waves 2,3 -> lo ----
            if (wave < 4) {
                const unsigned short* gsrc = (wave < 2) ? qh : ql;
                const int s = wave & 1;
                const size_t goff = (size_t)(row0 + s * 16) * D_K + kbase + laneoff;
                __builtin_amdgcn_global_load_lds(
                    (const AS1 unsigned int*)(const void*)(gsrc + goff),
                    (AS3 unsigned int*)(void*)(sA + (wave < 2 ? 0 : 1024) + s * 512),
                    16, 0, 0);
            }
            __syncthreads();

            // ---- fragments + 3-term MFMA ----
            bf16x8 ah[2], al[2];
#pragma unroll
            for (int i = 0; i < 2; ++i) {
                ah[i] = *(const bf16x8*)(sA + i * 512 + fragoff);
                al[i] = *(const bf16x8*)(sA + 1024 + i * 512 + fragoff);
            }
#pragma unroll
            for (int j = 0; j < 4; ++j) {
                const int sj = wave * 4 + j;
                bf16x8 bhj = *(const bf16x8*)(sB + sj * 512 + fragoff);
                bf16x8 blj = *(const bf16x8*)(sB + 16384 + sj * 512 + fragoff);
#pragma unroll
                for (int i = 0; i < 2; ++i) {
                    acc[pass][i][j] = __builtin_amdgcn_mfma_f32_16x16x32_bf16(ah[i], bhj, acc[pass][i][j], 0, 0, 0);
                    acc[pass][i][j] = __builtin_amdgcn_mfma_f32_16x16x32_bf16(ah[i], blj, acc[pass][i][j], 0, 0, 0);
                    acc[pass][i][j] = __builtin_amdgcn_mfma_f32_16x16x32_bf16(al[i], bhj, acc[pass][i][j], 0, 0, 0);
                }
            }
            __syncthreads();
        }
    }

    // ================= epilogue: logits -> softmax -> store =================
    // C layout (verified m89/m91): col = j*16 + rsel, row = i*16 + kq*4 + r.
    // 1) logits = 2*qp - p2[col]
    float p2v[2][4];
#pragma unroll
    for (int p = 0; p < 2; ++p)
#pragma unroll
        for (int j = 0; j < 4; ++j)
            p2v[p][j] = p2[p * 512 + wave * 64 + j * 16 + rsel];
#pragma unroll
    for (int p = 0; p < 2; ++p)
#pragma unroll
        for (int i = 0; i < 2; ++i)
#pragma unroll
            for (int j = 0; j < 4; ++j)
#pragma unroll
                for (int r = 0; r < 4; ++r)
                    acc[p][i][j][r] = 2.0f * acc[p][i][j][r] - p2v[p][j];

    // 2) per-row max: in-thread over (p,j), then over the 16 rsel lanes.
    float rmax[2][4];
#pragma unroll
    for (int i = 0; i < 2; ++i)
#pragma unroll
        for (int r = 0; r < 4; ++r) {
            float m = acc[0][i][0][r];
#pragma unroll
            for (int p = 0; p < 2; ++p)
#pragma unroll
                for (int j = 0; j < 4; ++j) m = fmaxf(m, acc[p][i][j][r]);
            rmax[i][r] = m;
        }
#pragma unroll
    for (int off = 1; off < 16; off <<= 1)
#pragma unroll
        for (int i = 0; i < 2; ++i)
#pragma unroll
            for (int r = 0; r < 4; ++r)
                rmax[i][r] = fmaxf(rmax[i][r], __shfl_xor(rmax[i][r], off));
    // cross-wave combine
    if (rsel == 0) {
#pragma unroll
        for (int i = 0; i < 2; ++i)
#pragma unroll
            for (int r = 0; r < 4; ++r)
                wred[wave * 32 + i * 16 + kq * 4 + r] = rmax[i][r];
    }
    __syncthreads();
#pragma unroll
    for (int i = 0; i < 2; ++i)
#pragma unroll
        for (int r = 0; r < 4; ++r) {
            const int lr = i * 16 + kq * 4 + r;
            float m = wred[lr];
#pragma unroll
            for (int w = 1; w < 8; ++w) m = fmaxf(m, wred[w * 32 + lr]);
            rmax[i][r] = m;
        }

    // 3) exp + per-row sum
    float rsum[2][4];
#pragma unroll
    for (int i = 0; i < 2; ++i)
#pragma unroll
        for (int r = 0; r < 4; ++r) rsum[i][r] = 0.0f;
#pragma unroll
    for (int p = 0; p < 2; ++p)
#pragma unroll
        for (int i = 0; i < 2; ++i)
#pragma unroll
            for (int j = 0; j < 4; ++j)
#pragma unroll
                for (int r = 0; r < 4; ++r) {
                    float e = __expf(acc[p][i][j][r] - rmax[i][r]);
                    acc[p][i][j][r] = e;
                    rsum[i][r] += e;
                }
#pragma unroll
    for (int off = 1; off < 16; off <<= 1)
#pragma unroll
        for (int i = 0; i < 2; ++i)
#pragma unroll
            for (int r = 0; r < 4; ++r)
                rsum[i][r] += __shfl_xor(rsum[i][r], off);
    if (rsel == 0) {
#pragma unroll
        for (int i = 0; i < 2; ++i)
#pragma unroll
            for (int r = 0; r < 4; ++r)
                wsum[wave * 32 + i * 16 + kq * 4 + r] = rsum[i][r];
    }
    __syncthreads();
    float inv[2][4];
#pragma unroll
    for (int i = 0; i < 2; ++i)
#pragma unroll
        for (int r = 0; r < 4; ++r) {
            const int lr = i * 16 + kq * 4 + r;
            float s = wsum[lr];
#pragma unroll
            for (int w = 1; w < 8; ++w) s += wsum[w * 32 + lr];
            inv[i][r] = 1.0f / s;
        }

    // 4) store final probabilities (only output traffic of the pipeline)
#pragma unroll
    for (int p = 0; p < 2; ++p)
#pragma unroll
        for (int j = 0; j < 4; ++j) {
            const int gc = p * 512 + wave * 64 + j * 16 + rsel;
#pragma unroll
            for (int i = 0; i < 2; ++i)
#pragma unroll
                for (int r = 0; r < 4; ++r) {
                    const int gr = row0 + i * 16 + kq * 4 + r;
                    __builtin_nontemporal_store(acc[p][i][j][r] * inv[i][r],
                                                &out[(size_t)gr * M_P + gc]);
                }
        }
}

// ---------------------------------------------------------------------------
// Fallback (tiny workspace): naive fp32 logits + separate softmax.
// ---------------------------------------------------------------------------
__global__ __launch_bounds__(256) void naive_logits_kernel(
    const float* __restrict__ query, const float* __restrict__ proto,
    float* __restrict__ out) {
    __shared__ float qs[D_K];
    int n = blockIdx.x;
    int t = threadIdx.x;
    ((float4*)qs)[t] = ((const float4*)(query + (size_t)n * D_K))[t];
    __syncthreads();
    float acc[4] = {0.f, 0.f, 0.f, 0.f};
    float pp[4] = {0.f, 0.f, 0.f, 0.f};
    for (int d = 0; d < D_K; d += 4) {
        float4 qv = *(const float4*)(qs + d);
#pragma unroll
        for (int j = 0; j < 4; ++j) {
            const float4 pv = *(const float4*)(proto + (size_t)(t + 256 * j) * D_K + d);
            acc[j] += qv.x * pv.x + qv.y * pv.y + qv.z * pv.z + qv.w * pv.w;
            pp[j] += pv.x * pv.x + pv.y * pv.y + pv.z * pv.z + pv.w * pv.w;
        }
    }
#pragma unroll
    for (int j = 0; j < 4; ++j)
        out[(size_t)n * M_P + t + 256 * j] = 2.0f * acc[j] - pp[j];
}

__global__ __launch_bounds__(256) void softmax_kernel(float* __restrict__ out) {
    const int lane = threadIdx.x & 63;
    int n = blockIdx.x * 4 + (threadIdx.x >> 6);
    for (int it = 0; it < 2; ++it, n += 8192) {
        float* row = out + (size_t)n * M_P;
        floatx4 v[4];
#pragma unroll
        for (int k = 0; k < 4; ++k)
            v[k] = *((const floatx4*)(row + k * 256) + lane);
        float mx = fmaxf(fmaxf(v[0].x, v[0].y), fmaxf(v[0].z, v[0].w));
#pragma unroll
        for (int k = 1; k < 4; ++k)
            mx = fmaxf(mx, fmaxf(fmaxf(v[k].x, v[k].y), fmaxf(v[k].z, v[k].w)));
#pragma unroll
        for (int off = 1; off < 64; off <<= 1) mx = fmaxf(mx, __shfl_xor(mx, off));
        float s = 0.0f;
#pragma unroll
        for (int k = 0; k < 4; ++k) {
            v[k].x = __expf(v[k].x - mx);
            v[k].y = __expf(v[k].y - mx);
            v[k].z = __expf(v[k].z - mx);
            v[k].w = __expf(v[k].w - mx);
            s += v[k].x + v[k].y + v[k].z + v[k].w;
        }
#pragma unroll
        for (int off = 1; off < 64; off <<= 1) s += __shfl_xor(s, off);
        const float inv = 1.0f / s;
#pragma unroll
        for (int k = 0; k < 4; ++k) {
            floatx4 o;
            o.x = v[k].x * inv; o.y = v[k].y * inv;
            o.z = v[k].z * inv; o.w = v[k].w * inv;
            __builtin_nontemporal_store(o, (floatx4*)(row + k * 256) + lane);
        }
    }
}

extern "C" void kernel_launch(void* const* d_in, const int* in_sizes, int n_in,
                              void* d_out, int out_size, void* d_ws, size_t ws_size,
                              hipStream_t stream) {
    const float* query = (const float*)d_in[0];
    const float* proto = (const float*)d_in[1];
    float* out = (float*)d_out;

    const size_t qElems = (size_t)N_Q * D_K;   // 16M
    const size_t pElems = (size_t)M_P * D_K;   // 1M
    const size_t needed = qElems * 2 * 2 + pElems * 2 * 2 + M_P * 4;  // ~68 MiB

    if (ws_size >= needed) {
        unsigned short* qh = (unsigned short*)d_ws;
        unsigned short* ql = qh + qElems;
        unsigned short* ph = ql + qElems;
        unsigned short* pl = ph + pElems;
        float* p2 = (float*)(pl + pElems);

        convert_all_kernel<<<2048 + M_P, 256, 0, stream>>>(
            query, qh, ql, proto, ph, pl, p2);
        fused_gemm_softmax_kernel<<<N_Q / 32, 512, 0, stream>>>(
            qh, ql, ph, pl, p2, out);
    } else {
        naive_logits_kernel<<<N_Q, 256, 0, stream>>>(query, proto, out);
        softmax_kernel<<<2048, 256, 0, stream>>>(out);
    }
}

// Round 7
// 229.923 us; speedup vs baseline: 1.3301x; 1.3301x over previous
//
#include <hip/hip_runtime.h>
#include <stdint.h>

#define N_Q 16384
#define M_P 1024
#define D_K 1024

typedef __attribute__((ext_vector_type(8))) __bf16 bf16x8;
typedef __attribute__((ext_vector_type(4))) float floatx4;
typedef __attribute__((ext_vector_type(8))) unsigned short ushort8v;

#define AS1 __attribute__((address_space(1)))
#define AS3 __attribute__((address_space(3)))

__device__ __forceinline__ unsigned short f2bf(float f) {
    unsigned int u = __float_as_uint(f);
    u += 0x7fffu + ((u >> 16) & 1u);   // round-to-nearest-even
    return (unsigned short)(u >> 16);
}
__device__ __forceinline__ float bf2f(unsigned short h) {
    return __uint_as_float(((unsigned int)h) << 16);
}

// ---------------------------------------------------------------------------
// Fused convert. Blocks [0,2048): query fp32 -> bf16 hi/lo, 4 float8s/thread.
// Blocks [2048,3072): proto rows + p2[m].  (~BW-bound, ~25-30 us)
// ---------------------------------------------------------------------------
__global__ __launch_bounds__(256) void convert_all_kernel(
    const float* __restrict__ query, unsigned short* __restrict__ qh,
    unsigned short* __restrict__ ql, const float* __restrict__ proto,
    unsigned short* __restrict__ ph, unsigned short* __restrict__ pl,
    float* __restrict__ p2) {
    __shared__ float sred[4];
    int b = blockIdx.x;
    int t = threadIdx.x;
    if (b < 2048) {
        size_t base = (size_t)b * 1024 + t;   // float8 index
#pragma unroll
        for (int k = 0; k < 4; ++k) {
            size_t idx = base + (size_t)k * 256;
            const floatx4* src = (const floatx4*)query + idx * 2;
            floatx4 v0 = __builtin_nontemporal_load(src);
            floatx4 v1 = __builtin_nontemporal_load(src + 1);
            ushort8v h, l;
            h[0] = f2bf(v0.x); l[0] = f2bf(v0.x - bf2f(h[0]));
            h[1] = f2bf(v0.y); l[1] = f2bf(v0.y - bf2f(h[1]));
            h[2] = f2bf(v0.z); l[2] = f2bf(v0.z - bf2f(h[2]));
            h[3] = f2bf(v0.w); l[3] = f2bf(v0.w - bf2f(h[3]));
            h[4] = f2bf(v1.x); l[4] = f2bf(v1.x - bf2f(h[4]));
            h[5] = f2bf(v1.y); l[5] = f2bf(v1.y - bf2f(h[5]));
            h[6] = f2bf(v1.z); l[6] = f2bf(v1.z - bf2f(h[6]));
            h[7] = f2bf(v1.w); l[7] = f2bf(v1.w - bf2f(h[7]));
            ((ushort8v*)qh)[idx] = h;   // re-read by GEMM: keep cacheable
            ((ushort8v*)ql)[idx] = l;
        }
    } else {
        int m = b - 2048;
        size_t base4 = (size_t)m * (D_K / 4) + t;
        float4 v = ((const float4*)proto)[base4];
        ushort4 h, l;
        h.x = f2bf(v.x); l.x = f2bf(v.x - bf2f(h.x));
        h.y = f2bf(v.y); l.y = f2bf(v.y - bf2f(h.y));
        h.z = f2bf(v.z); l.z = f2bf(v.z - bf2f(h.z));
        h.w = f2bf(v.w); l.w = f2bf(v.w - bf2f(h.w));
        ((ushort4*)ph)[base4] = h;
        ((ushort4*)pl)[base4] = l;
        float sq = v.x * v.x + v.y * v.y + v.z * v.z + v.w * v.w;
#pragma unroll
        for (int off = 1; off < 64; off <<= 1) sq += __shfl_xor(sq, off);
        if ((t & 63) == 0) sred[t >> 6] = sq;
        __syncthreads();
        if (t == 0) p2[m] = sred[0] + sred[1] + sred[2] + sred[3];
    }
}

// ---------------------------------------------------------------------------
// GEMM: logits[n,m] = 2 * sum_d q[n,d]*p[m,d] - p2[m], bf16 hi/lo 3-term.
// R7 structure: 128x128 block tile with TWO waves (128 threads); wave w owns
// rows [w*64,+64) x all 128 cols -> acc 4x8 (128 regs). Per kt per lane:
// 24 ds_read_b128 feed 96 MFMA (4.0 LDS-B/MFMA vs 5.33 for the R4 64x64
// wave tile) - attacks the MFMA:staging ratio that sets the m97 plateau.
// LDS still 32KB; 4 blocks/CU at __launch_bounds__(128,2); 2-wave barriers
// with 4 independent blocks/CU overlap the vmcnt drains.
// Staging keeps the R4-verified pattern: quad-coalesced global (lane quad =
// one row's 64B) + XOR swizzle -> measured 0 bank conflicts.
// XCD-aware grid: the 8 mt-blocks sharing an A-strip are 8 apart in
// blockIdx (same XCD under round-robin) -> A strip fetched ~once per XCD.
// ---------------------------------------------------------------------------
__global__ __launch_bounds__(128, 2) void gemm_logits_kernel(
    const unsigned short* __restrict__ qh, const unsigned short* __restrict__ ql,
    const unsigned short* __restrict__ ph, const unsigned short* __restrict__ pl,
    const float* __restrict__ p2, float* __restrict__ out) {
    __shared__ unsigned short lds[4 * 128 * 32];  // Ah | Al | Bh | Bl, 32 KB

    const int tid = threadIdx.x;
    const int wave = tid >> 6;   // 0,1
    const int lane = tid & 63;
    const int b = blockIdx.x;
    // XCD-aware: same-XCD neighbors (b, b+8, ..) share nt, sweep mt.
    const int mt = (b >> 3) & 7;
    const int nt = (b & 7) | ((b >> 6) << 3);
    const int row0 = nt * 128;
    const int col0 = mt * 128;

    unsigned short* sAh = lds;
    unsigned short* sAl = lds + 4096;
    unsigned short* sBh = lds + 8192;
    unsigned short* sBl = lds + 12288;

    // Staging: wave 0 -> A hi+lo (8 subtiles each), wave 1 -> B hi+lo.
    const unsigned short* gh = (wave == 0) ? qh : ph;
    const unsigned short* gl = (wave == 0) ? ql : pl;
    const int grow0 = (wave == 0) ? row0 : col0;
    unsigned short* dsth = (wave == 0) ? sAh : sBh;
    unsigned short* dstl = (wave == 0) ? sAl : sBl;

    // Quad-coalesced + XOR-swizzled staging source (R4-verified).
    const int rl = lane >> 2;
    const int cio = (lane & 3) ^ ((lane >> 3) & 3);
    const size_t laneoff = (size_t)rl * D_K + cio * 8;
    const unsigned short* gbh = gh + (size_t)grow0 * D_K + laneoff;
    const unsigned short* gbl = gl + (size_t)grow0 * D_K + laneoff;

    floatx4 zero = {0.0f, 0.0f, 0.0f, 0.0f};
    floatx4 acc[4][8];
#pragma unroll
    for (int i = 0; i < 4; ++i)
#pragma unroll
        for (int j = 0; j < 8; ++j) acc[i][j] = zero;

    const int rsel = lane & 15;
    const int kq = lane >> 4;
    const int gsw = 4 * rsel + (kq ^ ((rsel >> 1) & 3));
    const int fragoff = gsw * 8;  // shorts

    for (int kt = 0; kt < D_K / 32; ++kt) {
        const int kbase = kt * 32;
        // ---- stage global -> LDS: 16 async 16B/lane loads per wave ----
#pragma unroll
        for (int s = 0; s < 8; ++s) {
            const size_t go = (size_t)(s * 16) * D_K + kbase;
            __builtin_amdgcn_global_load_lds(
                (const AS1 unsigned int*)(const void*)(gbh + go),
                (AS3 unsigned int*)(void*)(dsth + s * 512), 16, 0, 0);
            __builtin_amdgcn_global_load_lds(
                (const AS1 unsigned int*)(const void*)(gbl + go),
                (AS3 unsigned int*)(void*)(dstl + s * 512), 16, 0, 0);
        }
        __syncthreads();

        // ---- fragments (swizzle-matched, conflict-free) + 3-term MFMA ----
        bf16x8 ah[4], al[4];
#pragma unroll
        for (int i = 0; i < 4; ++i) {
            const int aoff = (wave * 4 + i) * 512 + fragoff;
            ah[i] = *(const bf16x8*)(sAh + aoff);
            al[i] = *(const bf16x8*)(sAl + aoff);
        }
#pragma unroll
        for (int j = 0; j < 8; ++j) {
            const int boff = j * 512 + fragoff;
            bf16x8 bhj = *(const bf16x8*)(sBh + boff);
            bf16x8 blj = *(const bf16x8*)(sBl + boff);
#pragma unroll
            for (int i = 0; i < 4; ++i) {
                acc[i][j] = __builtin_amdgcn_mfma_f32_16x16x32_bf16(ah[i], bhj, acc[i][j], 0, 0, 0);
                acc[i][j] = __builtin_amdgcn_mfma_f32_16x16x32_bf16(ah[i], blj, acc[i][j], 0, 0, 0);
                acc[i][j] = __builtin_amdgcn_mfma_f32_16x16x32_bf16(al[i], bhj, acc[i][j], 0, 0, 0);
            }
        }
        __syncthreads();
    }

    // ---- epilogue: logits = 2*qp - p2[col] ----
    // C layout (verified m89/m91): col = lane&15, row = (lane>>4)*4 + reg
#pragma unroll
    for (int j = 0; j < 8; ++j) {
        const int gc = col0 + j * 16 + rsel;
        const float p2v = p2[gc];
#pragma unroll
        for (int i = 0; i < 4; ++i) {
            const int gr = row0 + wave * 64 + i * 16 + kq * 4;
#pragma unroll
            for (int r = 0; r < 4; ++r) {
                out[(size_t)(gr + r) * M_P + gc] = 2.0f * acc[i][j][r] - p2v;
            }
        }
    }
}

// ---------------------------------------------------------------------------
// Fallback (tiny workspace): naive fp32 logits + separate softmax.
// ---------------------------------------------------------------------------
__global__ __launch_bounds__(256) void naive_logits_kernel(
    const float* __restrict__ query, const float* __restrict__ proto,
    float* __restrict__ out) {
    __shared__ float qs[D_K];
    int n = blockIdx.x;
    int t = threadIdx.x;
    ((float4*)qs)[t] = ((const float4*)(query + (size_t)n * D_K))[t];
    __syncthreads();
    float acc[4] = {0.f, 0.f, 0.f, 0.f};
    float pp[4] = {0.f, 0.f, 0.f, 0.f};
    for (int d = 0; d < D_K; d += 4) {
        float4 qv = *(const float4*)(qs + d);
#pragma unroll
        for (int j = 0; j < 4; ++j) {
            const float4 pv = *(const float4*)(proto + (size_t)(t + 256 * j) * D_K + d);
            acc[j] += qv.x * pv.x + qv.y * pv.y + qv.z * pv.z + qv.w * pv.w;
            pp[j] += pv.x * pv.x + pv.y * pv.y + pv.z * pv.z + pv.w * pv.w;
        }
    }
#pragma unroll
    for (int j = 0; j < 4; ++j)
        out[(size_t)n * M_P + t + 256 * j] = 2.0f * acc[j] - pp[j];
}

// ---------------------------------------------------------------------------
// In-place row softmax, wave-per-row (no LDS/barriers). ~24 us measured.
// ---------------------------------------------------------------------------
__global__ __launch_bounds__(256) void softmax_kernel(float* __restrict__ out) {
    const int lane = threadIdx.x & 63;
    int n = blockIdx.x * 4 + (threadIdx.x >> 6);
    for (int it = 0; it < 2; ++it, n += 8192) {
        float* row = out + (size_t)n * M_P;
        floatx4 v[4];
#pragma unroll
        for (int k = 0; k < 4; ++k)
            v[k] = *((const floatx4*)(row + k * 256) + lane);
        float mx = fmaxf(fmaxf(v[0].x, v[0].y), fmaxf(v[0].z, v[0].w));
#pragma unroll
        for (int k = 1; k < 4; ++k)
            mx = fmaxf(mx, fmaxf(fmaxf(v[k].x, v[k].y), fmaxf(v[k].z, v[k].w)));
#pragma unroll
        for (int off = 1; off < 64; off <<= 1) mx = fmaxf(mx, __shfl_xor(mx, off));
        float s = 0.0f;
#pragma unroll
        for (int k = 0; k < 4; ++k) {
            v[k].x = __expf(v[k].x - mx);
            v[k].y = __expf(v[k].y - mx);
            v[k].z = __expf(v[k].z - mx);
            v[k].w = __expf(v[k].w - mx);
            s += v[k].x + v[k].y + v[k].z + v[k].w;
        }
#pragma unroll
        for (int off = 1; off < 64; off <<= 1) s += __shfl_xor(s, off);
        const float inv = 1.0f / s;
#pragma unroll
        for (int k = 0; k < 4; ++k) {
            floatx4 o;
            o.x = v[k].x * inv; o.y = v[k].y * inv;
            o.z = v[k].z * inv; o.w = v[k].w * inv;
            __builtin_nontemporal_store(o, (floatx4*)(row + k * 256) + lane);
        }
    }
}

extern "C" void kernel_launch(void* const* d_in, const int* in_sizes, int n_in,
                              void* d_out, int out_size, void* d_ws, size_t ws_size,
                              hipStream_t stream) {
    const float* query = (const float*)d_in[0];
    const float* proto = (const float*)d_in[1];
    float* out = (float*)d_out;

    const size_t qElems = (size_t)N_Q * D_K;   // 16M
    const size_t pElems = (size_t)M_P * D_K;   // 1M
    const size_t needed = qElems * 2 * 2 + pElems * 2 * 2 + M_P * 4;  // ~68 MiB

    if (ws_size >= needed) {
        unsigned short* qh = (unsigned short*)d_ws;
        unsigned short* ql = qh + qElems;
        unsigned short* ph = ql + qElems;
        unsigned short* pl = ph + pElems;
        float* p2 = (float*)(pl + pElems);

        convert_all_kernel<<<2048 + M_P, 256, 0, stream>>>(
            query, qh, ql, proto, ph, pl, p2);
        gemm_logits_kernel<<<(N_Q / 128) * (M_P / 128), 128, 0, stream>>>(
            qh, ql, ph, pl, p2, out);
    } else {
        naive_logits_kernel<<<N_Q, 256, 0, stream>>>(query, proto, out);
    }
    softmax_kernel<<<2048, 256, 0, stream>>>(out);
}

// Round 8
// 226.136 us; speedup vs baseline: 1.3523x; 1.0167x over previous
//
#include <hip/hip_runtime.h>
#include <stdint.h>

#define N_Q 16384
#define M_P 1024
#define D_K 1024

typedef __attribute__((ext_vector_type(8))) __bf16 bf16x8;
typedef __attribute__((ext_vector_type(4))) float floatx4;

#define AS1 __attribute__((address_space(1)))
#define AS3 __attribute__((address_space(3)))

__device__ __forceinline__ unsigned short f2bf(float f) {
    unsigned int u = __float_as_uint(f);
    u += 0x7fffu + ((u >> 16) & 1u);   // round-to-nearest-even
    return (unsigned short)(u >> 16);
}
__device__ __forceinline__ float bf2f(unsigned short h) {
    return __uint_as_float(((unsigned int)h) << 16);
}

// In-register fp32 -> bf16 hi/lo split (trunc-hi; lo captures the residual;
// lo itself truncated -> total per-element rel err ~2^-16, logit err ~1e-3).
__device__ __forceinline__ void split8(floatx4 f0, floatx4 f1,
                                       bf16x8* ah, bf16x8* al) {
    union { bf16x8 v; unsigned short s[8]; } H, L;
    float e[8] = {f0.x, f0.y, f0.z, f0.w, f1.x, f1.y, f1.z, f1.w};
#pragma unroll
    for (int j = 0; j < 8; ++j) {
        unsigned int u = __float_as_uint(e[j]);
        H.s[j] = (unsigned short)(u >> 16);
        float lo = e[j] - __uint_as_float(u & 0xffff0000u);
        L.s[j] = (unsigned short)(__float_as_uint(lo) >> 16);
    }
    *ah = H.v;
    *al = L.v;
}

// ---------------------------------------------------------------------------
// Proto-only convert: split fp32 -> bf16 hi/lo + p2[m]. One block per row.
// (Query split now happens inside the GEMM -> saves 128 MiB of HBM traffic
// and most of the old convert dispatch.)
// ---------------------------------------------------------------------------
__global__ __launch_bounds__(256) void convert_proto_kernel(
    const float* __restrict__ proto, unsigned short* __restrict__ ph,
    unsigned short* __restrict__ pl, float* __restrict__ p2) {
    __shared__ float sred[4];
    int m = blockIdx.x;
    int t = threadIdx.x;
    size_t base4 = (size_t)m * (D_K / 4) + t;
    float4 v = ((const float4*)proto)[base4];
    ushort4 h, l;
    h.x = f2bf(v.x); l.x = f2bf(v.x - bf2f(h.x));
    h.y = f2bf(v.y); l.y = f2bf(v.y - bf2f(h.y));
    h.z = f2bf(v.z); l.z = f2bf(v.z - bf2f(h.z));
    h.w = f2bf(v.w); l.w = f2bf(v.w - bf2f(h.w));
    ((ushort4*)ph)[base4] = h;
    ((ushort4*)pl)[base4] = l;
    float sq = v.x * v.x + v.y * v.y + v.z * v.z + v.w * v.w;
#pragma unroll
    for (int off = 1; off < 64; off <<= 1) sq += __shfl_xor(sq, off);
    if ((t & 63) == 0) sred[t >> 6] = sq;
    __syncthreads();
    if (t == 0) p2[m] = sred[0] + sred[1] + sred[2] + sred[3];
}

// ---------------------------------------------------------------------------
// GEMM: logits[n,m] = 2*sum_d q[n,d]*p[m,d] - p2[m]; A (query) staged as RAW
// FP32 into LDS and split to bf16 hi/lo in VGPRs at fragment time (VALU
// co-issues under MFMA, m114). B (proto) pre-split bf16 hi/lo.
// 128x128 tile, 2 waves, wave-tile 64x128; 3-term MFMA (drop ql*pl).
//
// A LDS layout: 16B granules; subtile = 16 rows x 8 granules; position
// p = r*8 + ((c) ^ (r&7)) -- staged with lane l of inst t fetching
// (row = t*8 + l>>3, granule c = (l&7)^(l>>3)). Fragment reads at
// p = rsel*8 + ((2kq+{0,1}) ^ (rsel&7)): uniform over the 8 bank-groups
// (conflict-free) and quad-coalesced on the global side.
// B keeps the R4-verified quad-coalesced + XOR-swizzle path (0 conflicts).
// XCD-aware grid: blocks 8 apart share nt -> A strip L2-resident per XCD
// (measured R7: FETCH halved).
// ---------------------------------------------------------------------------
__global__ __launch_bounds__(128, 2) void gemm_logits_kernel(
    const float* __restrict__ query,
    const unsigned short* __restrict__ ph, const unsigned short* __restrict__ pl,
    const float* __restrict__ p2, float* __restrict__ out) {
    __shared__ float sAf[128 * 32];             // 16 KB fp32 A tile
    __shared__ unsigned short sBh[128 * 32];    // 8 KB
    __shared__ unsigned short sBl[128 * 32];    // 8 KB

    const int tid = threadIdx.x;
    const int wave = tid >> 6;   // 0,1
    const int lane = tid & 63;
    const int b = blockIdx.x;
    const int mt = (b >> 3) & 7;
    const int nt = (b & 7) | ((b >> 6) << 3);
    const int row0 = nt * 128;
    const int col0 = mt * 128;

    // B staging mapping (R4-verified): quad-coalesced + XOR swizzle.
    const int rlB = lane >> 2;
    const int cioB = (lane & 3) ^ ((lane >> 3) & 3);
    const size_t laneoffB = (size_t)rlB * D_K + cioB * 8;
    const unsigned short* gBh = ph + (size_t)col0 * D_K + laneoffB;
    const unsigned short* gBl = pl + (size_t)col0 * D_K + laneoffB;

    // A staging mapping: 8 rows/inst, granule XOR within the row's 128B.
    const int rlA = lane >> 3;                  // 0..7
    const int cioA = (lane & 7) ^ rlA;          // 16B granule in row
    const float* gA = query + (size_t)(row0 + rlA) * D_K + cioA * 4;

    floatx4 zero = {0.0f, 0.0f, 0.0f, 0.0f};
    floatx4 acc[4][8];
#pragma unroll
    for (int i = 0; i < 4; ++i)
#pragma unroll
        for (int j = 0; j < 8; ++j) acc[i][j] = zero;

    const int rsel = lane & 15;
    const int kq = lane >> 4;
    // B fragment granule (4 granules/row of bf16).
    const int gswB = 4 * rsel + (kq ^ ((rsel >> 1) & 3));
    const int fragoffB = gswB * 8;  // shorts
    // A fragment granule positions (8 granules/row of fp32).
    const int pA0 = rsel * 8 + ((2 * kq) ^ (rsel & 7));
    const int pA1 = rsel * 8 + ((2 * kq + 1) ^ (rsel & 7));

    for (int kt = 0; kt < D_K / 32; ++kt) {
        const int kbase = kt * 32;
        // ---- stage global -> LDS (async, 16B/lane; 16 insts per wave) ----
        if (wave == 0) {
#pragma unroll
            for (int s = 0; s < 8; ++s)
#pragma unroll
                for (int t = 0; t < 2; ++t)
                    __builtin_amdgcn_global_load_lds(
                        (const AS1 unsigned int*)(const void*)(gA + (size_t)(s * 16 + t * 8) * D_K + kbase),
                        (AS3 unsigned int*)(void*)(sAf + s * 512 + t * 256), 16, 0, 0);
        } else {
#pragma unroll
            for (int s = 0; s < 8; ++s) {
                const size_t go = (size_t)(s * 16) * D_K + kbase;
                __builtin_amdgcn_global_load_lds(
                    (const AS1 unsigned int*)(const void*)(gBh + go),
                    (AS3 unsigned int*)(void*)(sBh + s * 512), 16, 0, 0);
                __builtin_amdgcn_global_load_lds(
                    (const AS1 unsigned int*)(const void*)(gBl + go),
                    (AS3 unsigned int*)(void*)(sBl + s * 512), 16, 0, 0);
            }
        }
        __syncthreads();

        // ---- A fragments: fp32 LDS reads + in-register hi/lo split ----
        bf16x8 ah[4], al[4];
#pragma unroll
        for (int i = 0; i < 4; ++i) {
            const int st = wave * 4 + i;
            floatx4 f0 = *(const floatx4*)(sAf + st * 512 + pA0 * 4);
            floatx4 f1 = *(const floatx4*)(sAf + st * 512 + pA1 * 4);
            split8(f0, f1, &ah[i], &al[i]);
        }
        // ---- B fragments + 3-term MFMA ----
#pragma unroll
        for (int j = 0; j < 8; ++j) {
            const int boff = j * 512 + fragoffB;
            bf16x8 bhj = *(const bf16x8*)(sBh + boff);
            bf16x8 blj = *(const bf16x8*)(sBl + boff);
#pragma unroll
            for (int i = 0; i < 4; ++i) {
                acc[i][j] = __builtin_amdgcn_mfma_f32_16x16x32_bf16(ah[i], bhj, acc[i][j], 0, 0, 0);
                acc[i][j] = __builtin_amdgcn_mfma_f32_16x16x32_bf16(ah[i], blj, acc[i][j], 0, 0, 0);
                acc[i][j] = __builtin_amdgcn_mfma_f32_16x16x32_bf16(al[i], bhj, acc[i][j], 0, 0, 0);
            }
        }
        __syncthreads();
    }

    // ---- epilogue: logits = 2*qp - p2[col] ----
    // C layout (verified m89/m91): col = lane&15, row = (lane>>4)*4 + reg
#pragma unroll
    for (int j = 0; j < 8; ++j) {
        const int gc = col0 + j * 16 + rsel;
        const float p2v = p2[gc];
#pragma unroll
        for (int i = 0; i < 4; ++i) {
            const int gr = row0 + wave * 64 + i * 16 + kq * 4;
#pragma unroll
            for (int r = 0; r < 4; ++r) {
                out[(size_t)(gr + r) * M_P + gc] = 2.0f * acc[i][j][r] - p2v;
            }
        }
    }
}

// ---------------------------------------------------------------------------
// Fallback (tiny workspace): naive fp32 logits + separate softmax.
// ---------------------------------------------------------------------------
__global__ __launch_bounds__(256) void naive_logits_kernel(
    const float* __restrict__ query, const float* __restrict__ proto,
    float* __restrict__ out) {
    __shared__ float qs[D_K];
    int n = blockIdx.x;
    int t = threadIdx.x;
    ((float4*)qs)[t] = ((const float4*)(query + (size_t)n * D_K))[t];
    __syncthreads();
    float acc[4] = {0.f, 0.f, 0.f, 0.f};
    float pp[4] = {0.f, 0.f, 0.f, 0.f};
    for (int d = 0; d < D_K; d += 4) {
        float4 qv = *(const float4*)(qs + d);
#pragma unroll
        for (int j = 0; j < 4; ++j) {
            const float4 pv = *(const float4*)(proto + (size_t)(t + 256 * j) * D_K + d);
            acc[j] += qv.x * pv.x + qv.y * pv.y + qv.z * pv.z + qv.w * pv.w;
            pp[j] += pv.x * pv.x + pv.y * pv.y + pv.z * pv.z + pv.w * pv.w;
        }
    }
#pragma unroll
    for (int j = 0; j < 4; ++j)
        out[(size_t)n * M_P + t + 256 * j] = 2.0f * acc[j] - pp[j];
}

// ---------------------------------------------------------------------------
// In-place row softmax, wave-per-row (no LDS/barriers). ~24 us measured.
// ---------------------------------------------------------------------------
__global__ __launch_bounds__(256) void softmax_kernel(float* __restrict__ out) {
    const int lane = threadIdx.x & 63;
    int n = blockIdx.x * 4 + (threadIdx.x >> 6);
    for (int it = 0; it < 2; ++it, n += 8192) {
        float* row = out + (size_t)n * M_P;
        floatx4 v[4];
#pragma unroll
        for (int k = 0; k < 4; ++k)
            v[k] = *((const floatx4*)(row + k * 256) + lane);
        float mx = fmaxf(fmaxf(v[0].x, v[0].y), fmaxf(v[0].z, v[0].w));
#pragma unroll
        for (int k = 1; k < 4; ++k)
            mx = fmaxf(mx, fmaxf(fmaxf(v[k].x, v[k].y), fmaxf(v[k].z, v[k].w)));
#pragma unroll
        for (int off = 1; off < 64; off <<= 1) mx = fmaxf(mx, __shfl_xor(mx, off));
        float s = 0.0f;
#pragma unroll
        for (int k = 0; k < 4; ++k) {
            v[k].x = __expf(v[k].x - mx);
            v[k].y = __expf(v[k].y - mx);
            v[k].z = __expf(v[k].z - mx);
            v[k].w = __expf(v[k].w - mx);
            s += v[k].x + v[k].y + v[k].z + v[k].w;
        }
#pragma unroll
        for (int off = 1; off < 64; off <<= 1) s += __shfl_xor(s, off);
        const float inv = 1.0f / s;
#pragma unroll
        for (int k = 0; k < 4; ++k) {
            floatx4 o;
            o.x = v[k].x * inv; o.y = v[k].y * inv;
            o.z = v[k].z * inv; o.w = v[k].w * inv;
            __builtin_nontemporal_store(o, (floatx4*)(row + k * 256) + lane);
        }
    }
}

extern "C" void kernel_launch(void* const* d_in, const int* in_sizes, int n_in,
                              void* d_out, int out_size, void* d_ws, size_t ws_size,
                              hipStream_t stream) {
    const float* query = (const float*)d_in[0];
    const float* proto = (const float*)d_in[1];
    float* out = (float*)d_out;

    const size_t pElems = (size_t)M_P * D_K;   // 1M
    const size_t needed = pElems * 2 * 2 + M_P * 4;  // ~4.2 MiB

    if (ws_size >= needed) {
        unsigned short* ph = (unsigned short*)d_ws;
        unsigned short* pl = ph + pElems;
        float* p2 = (float*)(pl + pElems);

        convert_proto_kernel<<<M_P, 256, 0, stream>>>(proto, ph, pl, p2);
        gemm_logits_kernel<<<(N_Q / 128) * (M_P / 128), 128, 0, stream>>>(
            query, ph, pl, p2, out);
    } else {
        naive_logits_kernel<<<N_Q, 256, 0, stream>>>(query, proto, out);
    }
    softmax_kernel<<<2048, 256, 0, stream>>>(out);
}